// Round 13
// baseline (373.208 us; speedup 1.0000x reference)
//
#include <hip/hip_runtime.h>
#include <hip/hip_bf16.h>
#include <utility>

// ---------------------------------------------------------------------------
// BatteriesInteractionBlock: equivariant tensor-product message passing.
//   N=10000 nodes, E=160000 edges, C=32 channels, 16 irreps (L_MAX=3),
//   34 CG paths, scatter-sum over dst, then 512x512 linear. Output f32.
//
// Round-13 = BISECT: r11 (365us known-good) + nfp pre-pack ONLY.
//   - prep_nfp: nf packed to bf16-pair dwords [N][10][32] (12.8MB).
//     Edge gather: 5x b128 global loads + 5x b128 LDS stores, no cvt.
//     x2s relaid [el(16)][ip(10)][c(32)]; XOR swizzle commutes (bits 2-4).
//   - everything else is r11 VERBATIM: single 16-edge tile, cg in LDS,
//     scalar wv ownership, distributed B + batched bpermute two-pass,
//     dot2 a-comp, dst-sorted run-flush epilogue, r11 lin_kernel.
//   r12 bundled 3 changes and broke; this isolates the big lever.
// ---------------------------------------------------------------------------

#define NPATH 34
#define TOTCGF 4174

typedef __attribute__((ext_vector_type(2))) float f32x2;
typedef __attribute__((ext_vector_type(4))) float f32x4;
typedef __attribute__((ext_vector_type(4))) unsigned u32x4;
typedef __attribute__((ext_vector_type(8))) short short8;

// path tables: (l1,l2,l3) in reference order (sorted by l1)
constexpr int PL1[NPATH] = {0,0,0,0, 1,1,1,1,1,1,1,1,1, 2,2,2,2,2,2,2,2,2,2,2, 3,3,3,3,3,3,3,3,3,3};
constexpr int PL2[NPATH] = {0,1,2,3, 0,1,1,1,2,2,2,3,3, 0,1,1,1,2,2,2,2,3,3,3, 0,1,1,2,2,2,3,3,3,3};
constexpr int PL3[NPATH] = {0,1,2,3, 1,0,1,2,1,2,3,2,3, 2,1,2,3,0,1,2,3,1,2,3, 3,2,3,1,2,3,0,1,2,3};
// pair-padded cg offsets: per path size S3*S2*(S1+1), layout [k][j][i(pad even)]
constexpr int PCGF[NPATH] = {0,2,20,70, 168,180,192,228,288,348,448,588,728,
                             924,954,1008,1098,1224,1254,1344,1494,1704,1830,2040,
                             2334,2390,2510,2678,2798,2998,3278,3334,3502,3782};
// i-pair slot offsets per l1 block (widths {1,2,3,4}, 10 total)
constexpr int PO1A[4] = {0, 1, 3, 6};

__device__ __forceinline__ short f2bf(float f){
  unsigned u = __float_as_uint(f);
  unsigned r = (u + 0x7fffu + ((u >> 16) & 1u)) >> 16;
  return (short)r;
}

// ---- packed-math helpers (VOP3P asm verified on-device rounds 3-11) -------
__device__ __forceinline__ f32x2 pk_fma(f32x2 a, f32x2 x, f32x2 b){
  asm("v_pk_fma_f32 %0, %1, %2, %0" : "+v"(a) : "v"(x), "v"(b));
  return a;
}
__device__ __forceinline__ unsigned cvt_pk_bf16(float lo, float hi){
  unsigned r;
  asm("v_cvt_pk_bf16_f32 %0, %1, %2" : "=v"(r) : "v"(lo), "v"(hi));
  return r;
}
// c += a.lo*b.lo + a.hi*b.hi   (2x bf16 FMA, f32 accumulate)
__device__ __forceinline__ float dot2bf(unsigned a, unsigned b, float c){
  asm("v_dot2_f32_bf16 %0, %1, %2, %0" : "+v"(c) : "v"(a), "v"(b));
  return c;
}

// ------------------------------ prep_cgf -----------------------------------
__device__ double factd(int n){
  double f = 1.0;
  for (int i = 2; i <= n; i++) f *= (double)i;
  return f;
}

__device__ double cg_complex(int j1,int m1,int j2,int m2,int j3,int m3){
  if (m1 + m2 != m3) return 0.0;
  int dj = j1 - j2; if (dj < 0) dj = -dj;
  if (j3 < dj || j3 > j1 + j2) return 0.0;
  double pre = sqrt((double)(2*j3+1) * factd(j3+j1-j2) * factd(j3-j1+j2) *
                    factd(j1+j2-j3) / factd(j1+j2+j3+1));
  pre *= sqrt(factd(j3+m3)*factd(j3-m3)*factd(j1-m1)*factd(j1+m1)*
              factd(j2-m2)*factd(j2+m2));
  int k0 = 0;
  if (j2-j3-m1 > k0) k0 = j2-j3-m1;
  if (j1+m2-j3 > k0) k0 = j1+m2-j3;
  int k1 = j1+j2-j3;
  if (j1-m1 < k1) k1 = j1-m1;
  if (j2+m2 < k1) k1 = j2+m2;
  double s = 0.0;
  for (int k = k0; k <= k1; k++){
    double d = factd(k)*factd(j1+j2-j3-k)*factd(j1-m1-k)*factd(j2+m2-k)*
               factd(j3-j2+m1+k)*factd(j3-j1-m2+k);
    s += ((k & 1) ? -1.0 : 1.0) / d;
  }
  return pre * s;
}

struct Uent { int m; double re, im; };

__device__ int urow(int l, int a, Uent* o){
  const double s2 = 0.70710678118654752440;
  int ra = a - l;
  if (ra == 0){ o[0] = {0, 1.0, 0.0}; return 1; }
  if (ra > 0){
    int m = ra;
    o[0] = { -m, s2, 0.0 };
    o[1] = {  m, (m & 1) ? -s2 : s2, 0.0 };
    return 2;
  }
  int m = -ra;
  o[0] = { -m, 0.0, s2 };
  o[1] = {  m, 0.0, (m & 1) ? s2 : -s2 };
  return 2;
}

__device__ float real_cg(int l1, int l2, int l3, int i, int j, int k){
  Uent u1[2], u2[2], u3[2];
  int n1 = urow(l1, i, u1), n2 = urow(l2, j, u2), n3 = urow(l3, k, u3);
  double sre = 0.0, sim = 0.0;
  for (int a = 0; a < n1; a++)
    for (int b = 0; b < n2; b++)
      for (int c = 0; c < n3; c++){
        double cr = u1[a].re*u2[b].re - u1[a].im*u2[b].im;
        double ci = u1[a].re*u2[b].im + u1[a].im*u2[b].re;
        double tr = cr*u3[c].re + ci*u3[c].im;   // times conj(u3)
        double ti = ci*u3[c].re - cr*u3[c].im;
        double cgv = cg_complex(l1, u1[a].m, l2, u2[b].m, l3, u3[c].m);
        sre += tr*cgv; sim += ti*cgv;
      }
  return (float)((((l1+l2+l3) & 1) == 0) ? sre : sim);
}

// writes cgf[slot] with slot = PCGF[p] + (k*S2 + j)*(S1+1) + i  (i pad -> 0)
__global__ void prep_cgf(float* __restrict__ cgf){
  int idx = blockIdx.x * blockDim.x + threadIdx.x;
  if (idx >= TOTCGF) return;
  int p = 0;
  for (int q = 1; q < NPATH; q++) if (idx >= PCGF[q]) p = q;
  const int l1 = PL1[p], l2 = PL2[p], l3 = PL3[p];
  const int S1 = 2*l1+1, S2 = 2*l2+1, S1p = S1+1;
  int q  = idx - PCGF[p];
  int kkj = q / S1p;
  int ii  = q - kkj*S1p;
  float v = 0.f;
  if (ii < S1){
    int kk = kkj / S2;
    int j  = kkj - kk*S2;
    v = real_cg(l1, l2, l3, ii, j, kk);
  }
  cgf[idx] = v;
}

// ------------------------------ prep_w -------------------------------------
// wt[p][d][c] = bf16(tpw[p][c][d]);  Wb[o][ia] = bf16(W[o][(ia&31)*16 + (ia>>5)])
__global__ void prep_w(const float* __restrict__ tpw, const float* __restrict__ lw,
                       short* __restrict__ wt, short* __restrict__ Wb){
  int idx = blockIdx.x * blockDim.x + threadIdx.x;
  if (idx < NPATH*1024){
    int c = idx & 31, d = (idx >> 5) & 31, p = idx >> 10;
    wt[idx] = f2bf(tpw[(p << 10) + c*32 + d]);
  } else if (idx < NPATH*1024 + 512*512){
    int q = idx - NPATH*1024;
    int o = q >> 9, ia = q & 511;
    Wb[q] = f2bf(lw[o*512 + ((ia & 31) << 4) + (ia >> 5)]);
  }
}

// ------------------------------ prep_nfp -----------------------------------
// nfp[n][ip][c] = {bf16 x[n][c][i0(ip)], bf16 x[n][c][i1(ip)] or 0}
__global__ void prep_nfp(const float* __restrict__ nf, unsigned* __restrict__ nfp,
                         int N){
  int idx = blockIdx.x * blockDim.x + threadIdx.x;
  if (idx >= N * 320) return;
  int n = idx / 320, q = idx - n*320;
  int ip = q >> 5, c = q & 31;
  const int i0tab[10] = {0,1,3,4,6,8,9,11,13,15};
  const int i1tab[10] = {-1,2,-1,5,7,-1,10,12,14,-1};
  const float* row = nf + (size_t)n*512 + c*16;
  float lo = row[i0tab[ip]];
  float hi = (i1tab[ip] >= 0) ? row[i1tab[ip]] : 0.f;
  nfp[idx] = cvt_pk_bf16(lo, hi);
}

// --------------------------- sort-by-dst prep ------------------------------
__global__ void k_count(const int* __restrict__ ei, int* __restrict__ cnt, int E){
  int e = blockIdx.x*256 + threadIdx.x;
  if (e < E) atomicAdd(&cnt[ei[E + e]], 1);
}

__global__ void k_scan(int* __restrict__ cnt, int N){
  __shared__ int part[256];
  const int t = threadIdx.x;
  const int base = t * 40;
  int loc[40];
  int s = 0;
  #pragma unroll
  for (int q = 0; q < 40; q++){
    int idx = base + q;
    int v = (idx < N) ? cnt[idx] : 0;
    loc[q] = s; s += v;
  }
  part[t] = s;
  __syncthreads();
  for (int d = 1; d < 256; d <<= 1){
    int v = (t >= d) ? part[t - d] : 0;
    __syncthreads();
    part[t] += v;
    __syncthreads();
  }
  int pre = (t == 0) ? 0 : part[t - 1];
  #pragma unroll
  for (int q = 0; q < 40; q++){
    int idx = base + q;
    if (idx < N) cnt[idx] = pre + loc[q];
  }
}

__global__ void k_fill(const int* __restrict__ ei, int* __restrict__ cur,
                       int* __restrict__ perm, int E){
  int e = blockIdx.x*256 + threadIdx.x;
  if (e < E){
    int pos = atomicAdd(&cur[ei[E + e]], 1);
    perm[pos] = e;
  }
}

// --------------------------- path expansion helper -------------------------
template<typename F, size_t... I>
__device__ __forceinline__ void for_each_path(F&& f, std::index_sequence<I...>){
  (f(std::integral_constant<size_t, I>{}), ...);
}

// row swizzle for x2s: bits 2-4 of dword index, keeps b128 alignment
__device__ __forceinline__ int xswz(int r){
  return ((r & 3) << 2) | ((r & 1) << 4);
}

// ------------------------------ edge kernel --------------------------------
// 256 threads (4 waves), 16 dst-sorted edges/block. kg%4==wv wave split
// (wv scalarized). Lane role: lw = lane&15 (edge), g = lane>>4 (ch chunk).
__global__ __launch_bounds__(256, 4) void edge_kernel(
    const unsigned* __restrict__ nfp, const int* __restrict__ ei,
    const float* __restrict__ ev, const float* __restrict__ cgfg,
    const short* __restrict__ wt, const int* __restrict__ perm,
    float* __restrict__ accb, int E, int N)
{
  // phase1: x2s[16][10][32] u32 [0,20480) + Ydup f32x2[16][17] [20480,22656)
  // phase2: acc_l[16][256] f32 [0,16384)   (time-disjoint overlay of x2s)
  __shared__ __align__(16) char u_lds[22656];
  unsigned* x2s   = (unsigned*)u_lds;
  f32x2*    Yl2   = (f32x2*)(u_lds + 20480);
  float*    acc_l = (float*)u_lds;
  __shared__ __align__(16) float cgl[TOTCGF];          // 16696 B
  __shared__ int sdst[16];

  const int t    = threadIdx.x;
  const int lane = t & 63;
  const int wv   = __builtin_amdgcn_readfirstlane(t >> 6);  // SCALAR wave id
  const int e0   = blockIdx.x * 16;

  // ---- prologue: stage cg table into LDS (17 coalesced loads/thread) ----
  for (int i = t; i < TOTCGF; i += 256) cgl[i] = cgfg[i];

  // ---- prologue: permuted edge meta + Y (first 16 threads) ----
  if (t < 16){
    int eg = e0 + t;
    int pe = (eg < E) ? perm[eg] : -1;
    float vx = 0.f, vy = 0.f, vz = 0.f; int dn = -1;
    if (pe >= 0){
      vx = ev[pe*3]; vy = ev[pe*3+1]; vz = ev[pe*3+2];
      dn = ei[E + pe];
    }
    float nrm = sqrtf(vx*vx + vy*vy + vz*vz);
    float inv = 1.0f / fmaxf(nrm, 1e-8f);
    float x = vx*inv, y = vy*inv, z = vz*inv;
    float x2 = x*x, y2 = y*y, z2 = z*z;
    float ys[16];
    ys[0]  = 0.28209479177387814f;
    ys[1]  = 0.4886025119029199f * y;
    ys[2]  = 0.4886025119029199f * z;
    ys[3]  = 0.4886025119029199f * x;
    ys[4]  = 1.0925484305920792f * x * y;
    ys[5]  = 1.0925484305920792f * y * z;
    ys[6]  = 0.31539156525252005f * (3.f*z2 - 1.f);
    ys[7]  = 1.0925484305920792f * x * z;
    ys[8]  = 0.5462742152960396f * (x2 - y2);
    ys[9]  = 0.5900435899266435f * y * (3.f*x2 - y2);
    ys[10] = 2.890611442640554f * x * y * z;
    ys[11] = 0.4570457994644658f * y * (5.f*z2 - 1.f);
    ys[12] = 0.3731763325901154f * z * (5.f*z2 - 3.f);
    ys[13] = 0.4570457994644658f * x * (5.f*z2 - 1.f);
    ys[14] = 1.445305721320277f * z * (x2 - y2);
    ys[15] = 0.5900435899266435f * x * (x2 - 3.f*y2);
    #pragma unroll
    for (int j = 0; j < 16; j++) Yl2[t*17 + j] = (f32x2){ys[j], ys[j]};
    sdst[t] = dn;
  }

  // ---- prologue: packed x gather, b128 loads + b128 LDS stores ----
  {
    const int el = t >> 4, c0 = t & 15;
    int eg = e0 + el;
    int pe = (eg < E) ? perm[eg] : -1;
    int s  = (pe >= 0) ? ei[pe] : 0;
    const unsigned* xb = nfp + (size_t)s * 320;
    const int sw = xswz(el);
    #pragma unroll
    for (int b = 0; b < 5; b++){
      const int q = c0*20 + b*4;           // q%4==0; sw bits 2-4 commute
      u32x4 v = *(const u32x4*)(xb + q);
      *(u32x4*)&x2s[el*320 + (q ^ sw)] = v;
    }
  }

  f32x4 accm[4][2];
  #pragma unroll
  for (int q = 0; q < 4; q++){
    accm[q][0] = (f32x4){0.f,0.f,0.f,0.f};
    accm[q][1] = (f32x4){0.f,0.f,0.f,0.f};
  }

  __syncthreads();   // cgl / x2s / Yl2 / sdst visible

  const int lw   = lane & 15;
  const int g    = lane >> 4;
  const int swr  = xswz(lw);
  const int lwx4 = lw * 4;          // bpermute byte index base

  unsigned xs[8][4] = {};

  auto pbody = [&](auto pc){
    constexpr int P   = (int)decltype(pc)::value;
    constexpr int L1v = PL1[P], L2v = PL2[P], L3v = PL3[P];
    constexpr int S1 = 2*L1v+1, S2 = 2*L2v+1, S3 = 2*L3v+1;
    constexpr int O2 = L2v*L2v, O3 = L3v*L3v;
    constexpr int S1p  = S1 + 1;
    constexpr int S1p2 = S1p / 2;
    constexpr int CGF  = PCGF[P];
    constexpr int PO   = PO1A[L1v];

    // ---- group head: x fragments LDS -> registers ----
    if constexpr (P == 0 || PL1[P] != PL1[P-1]){
      #pragma unroll
      for (int ip = 0; ip < S1p2; ip++){
        const int base = lw*320 + (PO + ip)*32;
        u32x4 xlo = *(const u32x4*)&x2s[base + ((8*g)     ^ swr)];
        u32x4 xhi = *(const u32x4*)&x2s[base + ((8*g + 4) ^ swr)];
        xs[0][ip] = xlo[0]; xs[1][ip] = xlo[1];
        xs[2][ip] = xlo[2]; xs[3][ip] = xlo[3];
        xs[4][ip] = xhi[0]; xs[5][ip] = xhi[1];
        xs[6][ip] = xhi[2]; xs[7][ip] = xhi[3];
      }
    }

    // wave participates? (wv is SGPR -> scalar branch)
    bool hasrow;
    if constexpr (S3 >= 4) hasrow = true;
    else hasrow = (((unsigned)(wv - O3) & 3u) < (unsigned)S3);
    if (!hasrow) return;

    // weight fragments (global, L2-hot)
    const short8 bw0 = *(const short8*)(wt + (size_t)(P*32 +      lw)*32 + g*8);
    const short8 bw1 = *(const short8*)(wt + (size_t)(P*32 + 16 + lw)*32 + g*8);

    // ---- pass A: B-fragments for ALL owned k-rows (bpermutes batched) ----
    unsigned bqA[4][4];
    #pragma unroll
    for (int kl = 0; kl < S3; kl++){
      if (((O3 + kl) & 3) == wv){        // SCALAR compare -> s_cbranch
        const int ks = (O3 + kl) >> 2;   // compile-time per kl
        unsigned bq_own = 0;
        if (g < S1p2){
          f32x2 bacc = {0.f, 0.f};
          #pragma unroll
          for (int j = 0; j < S2; j++)
            bacc = pk_fma(bacc,
                          *(const f32x2*)&cgl[CGF + (kl*S2 + j)*S1p + 2*g],
                          Yl2[lw*17 + O2 + j]);
          bq_own = cvt_pk_bf16(bacc.x, bacc.y);
        }
        #pragma unroll
        for (int ip = 0; ip < S1p2; ip++)
          bqA[ks][ip] = (unsigned)__builtin_amdgcn_ds_bpermute(lwx4 + 64*ip,
                                                               (int)bq_own);
      }
    }

    // ---- pass B: a-comp (dot2) + MFMA per owned k-row ----
    #pragma unroll
    for (int kl = 0; kl < S3; kl++){
      if (((O3 + kl) & 3) == wv){
        const int ks = (O3 + kl) >> 2;
        float ac[8];
        #pragma unroll
        for (int q = 0; q < 8; q++) ac[q] = 0.f;
        #pragma unroll
        for (int ip = 0; ip < S1p2; ip++){
          #pragma unroll
          for (int q = 0; q < 8; q++)
            ac[q] = dot2bf(xs[q][ip], bqA[ks][ip], ac[q]);
        }
        union { unsigned u[4]; short8 s; } afu;
        afu.u[0] = cvt_pk_bf16(ac[0], ac[1]);
        afu.u[1] = cvt_pk_bf16(ac[2], ac[3]);
        afu.u[2] = cvt_pk_bf16(ac[4], ac[5]);
        afu.u[3] = cvt_pk_bf16(ac[6], ac[7]);
        accm[ks][0] = __builtin_amdgcn_mfma_f32_16x16x32_bf16(afu.s, bw0, accm[ks][0], 0, 0, 0);
        accm[ks][1] = __builtin_amdgcn_mfma_f32_16x16x32_bf16(afu.s, bw1, accm[ks][1], 0, 0, 0);
      }
    }
  };
  for_each_path(pbody, std::make_index_sequence<NPATH>{});

  __syncthreads();   // all x2s reads done before acc_l overlay

  // ---- epilogue: two half-tiles (kg 0..7 then 8..15), run-flush each ----
  #pragma unroll
  for (int half = 0; half < 2; half++){
    #pragma unroll
    for (int ks2 = 0; ks2 < 2; ks2++){
      const int ks = half*2 + ks2;
      const int kg = wv + 4*ks;
      #pragma unroll
      for (int dt2 = 0; dt2 < 2; dt2++){
        const int d = dt2*16 + lw;
        #pragma unroll
        for (int r = 0; r < 4; r++){
          const int e = 4*g + r;
          acc_l[(e*256 + (kg & 7)*32 + d) ^ (g << 3)] = accm[ks][dt2][r];
        }
      }
    }
    __syncthreads();
    {
      const int c = t;
      float v = 0.f; int prev = -2;
      #pragma unroll
      for (int s = 0; s < 16; s++){
        int dn = __builtin_amdgcn_readfirstlane(sdst[s]);  // block-uniform
        float av = acc_l[(s*256 + c) ^ (((s >> 2) & 3) << 3)];
        if (dn != prev){
          if (prev >= 0) unsafeAtomicAdd(accb + (size_t)prev*512 + half*256 + c, v);
          v = 0.f; prev = dn;
        }
        v += av;
      }
      if (prev >= 0) unsafeAtomicAdd(accb + (size_t)prev*512 + half*256 + c, v);
    }
    if (half == 0) __syncthreads();   // flush reads done before next writes
  }
}

// ------------------------------ linear kernel ------------------------------
__global__ __launch_bounds__(256, 4) void lin_kernel(
    const float* __restrict__ accb, const short* __restrict__ Wb,
    const float* __restrict__ bias, float* __restrict__ out, int N)
{
  __shared__ __align__(16) short As[64][32];
  __shared__ __align__(16) short Ws[64][32];
  const int t = threadIdx.x;
  const int lane = t & 63, wv = t >> 6;
  const int n0 = blockIdx.x * 64, o0 = blockIdx.y * 64;
  f32x4 acc4[4];
  #pragma unroll
  for (int q = 0; q < 4; q++) acc4[q] = (f32x4){0.f, 0.f, 0.f, 0.f};

  const int nn = t >> 2, kq = (t & 3) * 8;
  for (int kc = 0; kc < 16; kc++){
    __syncthreads();
    {
      short8 v8;
      int gn = n0 + nn;
      if (gn < N){
        const float* sp = accb + (size_t)gn*512 + kc*32 + kq;
        f32x4 f0 = ((const f32x4*)sp)[0], f1 = ((const f32x4*)sp)[1];
        v8[0] = f2bf(f0[0]); v8[1] = f2bf(f0[1]); v8[2] = f2bf(f0[2]); v8[3] = f2bf(f0[3]);
        v8[4] = f2bf(f1[0]); v8[5] = f2bf(f1[1]); v8[6] = f2bf(f1[2]); v8[7] = f2bf(f1[3]);
      } else {
        #pragma unroll
        for (int q = 0; q < 8; q++) v8[q] = 0;
      }
      *(short8*)&As[nn][kq] = v8;
      *(short8*)&Ws[nn][kq] = *(const short8*)(Wb + (size_t)(o0 + nn)*512 + kc*32 + kq);
    }
    __syncthreads();
    const short8 af = *(const short8*)&As[wv*16 + (lane & 15)][(lane >> 4) * 8];
    #pragma unroll
    for (int ct = 0; ct < 4; ct++){
      short8 bf8 = *(const short8*)&Ws[ct*16 + (lane & 15)][(lane >> 4) * 8];
      acc4[ct] = __builtin_amdgcn_mfma_f32_16x16x32_bf16(af, bf8, acc4[ct], 0, 0, 0);
    }
  }

  #pragma unroll
  for (int ct = 0; ct < 4; ct++){
    int o = o0 + ct*16 + (lane & 15);
    float bb = bias[o];
    #pragma unroll
    for (int r = 0; r < 4; r++){
      int n = n0 + wv*16 + (lane >> 4)*4 + r;
      if (n < N)
        out[(size_t)n*512 + o] = acc4[ct][r] + bb;
    }
  }
}

// ------------------------------ launcher -----------------------------------
extern "C" void kernel_launch(void* const* d_in, const int* in_sizes, int n_in,
                              void* d_out, int out_size, void* d_ws, size_t ws_size,
                              hipStream_t stream) {
  const float* nf  = (const float*)d_in[0];   // node_features (N,32,16) f32
  const int*   ei  = (const int*)d_in[1];     // edge_index (2,E) i32
  const float* ev  = (const float*)d_in[2];   // edge_vectors (E,3) f32
  const float* tpw = (const float*)d_in[3];   // tp_weights (34,32,32) f32
  const float* lw  = (const float*)d_in[4];   // linear_w (512,512) f32
  const float* lb  = (const float*)d_in[5];   // linear_b (512,) f32

  const int N = in_sizes[0] / 512;
  const int E = in_sizes[1] / 2;

  char* ws = (char*)d_ws;
  size_t off = 0;
  float* accb = (float*)(ws + off);
  off += (size_t)N * 512 * 4;          off = (off + 255) & ~(size_t)255;
  float* cgfg = (float*)(ws + off);
  off += (size_t)TOTCGF * 4;           off = (off + 255) & ~(size_t)255;
  short* wt   = (short*)(ws + off);
  off += (size_t)NPATH * 1024 * 2;     off = (off + 255) & ~(size_t)255;
  short* Wb   = (short*)(ws + off);
  off += (size_t)512 * 512 * 2;        off = (off + 255) & ~(size_t)255;
  int* cnt    = (int*)(ws + off);
  off += (size_t)N * 4;                off = (off + 255) & ~(size_t)255;
  int* perm   = (int*)(ws + off);
  off += (size_t)E * 4;                off = (off + 255) & ~(size_t)255;
  unsigned* nfp = (unsigned*)(ws + off);
  off += (size_t)N * 320 * 4;
  if (off > ws_size) return;  // workspace too small: fail loudly via validation

  hipMemsetAsync(accb, 0, (size_t)N * 512 * 4, stream);
  hipMemsetAsync(cnt, 0, (size_t)N * 4, stream);
  k_count<<<(E + 255) / 256, 256, 0, stream>>>(ei, cnt, E);
  k_scan<<<1, 256, 0, stream>>>(cnt, N);
  k_fill<<<(E + 255) / 256, 256, 0, stream>>>(ei, cnt, perm, E);
  prep_cgf<<<(TOTCGF + 255) / 256, 256, 0, stream>>>(cgfg);
  prep_w<<<(NPATH*1024 + 512*512 + 255) / 256, 256, 0, stream>>>(tpw, lw, wt, Wb);
  prep_nfp<<<(N*320 + 255) / 256, 256, 0, stream>>>(nf, nfp, N);
  edge_kernel<<<(E + 15) / 16, 256, 0, stream>>>(nfp, ei, ev, cgfg, wt, perm,
                                                 accb, E, N);
  lin_kernel<<<dim3((N + 63) / 64, 8), 256, 0, stream>>>(accb, Wb, lb,
                                                         (float*)d_out, N);
}

// Round 16
// 361.714 us; speedup vs baseline: 1.0318x; 1.0318x over previous
//
#include <hip/hip_runtime.h>
#include <hip/hip_bf16.h>
#include <utility>

// ---------------------------------------------------------------------------
// BatteriesInteractionBlock: equivariant tensor-product message passing.
//   N=10000 nodes, E=160000 edges, C=32 channels, 16 irreps (L_MAX=3),
//   34 CG paths, scatter-sum over dst, then 512x512 linear. Output f32.
//
// FINAL (round 16) = round-9 kernel restored verbatim (best known-good,
// 362.65us PASS, absmax 0.0078125). 1.8x over the round-2 baseline (651us).
//   - prep kernels: real CG blocks (pair-padded f32), bf16 weight tables,
//     dst-sorted edge permutation (count/scan/fill).
//   - edge_kernel (16 dst-sorted edges / 256 thr): cg staged in LDS;
//     x gathered once -> bf16-pair packed, XOR-swizzled LDS; SCALAR
//     (readfirstlane) wave ownership of k-rows (kg%4==wv); B-comp
//     distributed across g-lanes + ds_bpermute broadcast; a-comp via
//     v_dot2_f32_bf16; per-lane MFMA A-fragments -> mfma_f32_16x16x32_bf16;
//     messages -> swizzled LDS tile, run-flush = ~1 atomic per (dst,chan).
//   - lin_kernel: bf16 MFMA GEMM acc @ Wb^T + bias -> f32 out.
// Residual profile: VALUBusy ~56%, MfmaUtil 7.5%, HBM 9%, conflicts 1.2e7 —
// latency-stall floor of this decomposition at 4 waves/SIMD; four attempts
// to break it (coop B-comp, two-pass ILP, bf16-cg LDS cut, direct-global x)
// were neutral or broke correctness.
// ---------------------------------------------------------------------------

#define NPATH 34
#define TOTCGF 4174

typedef __attribute__((ext_vector_type(2))) float f32x2;
typedef __attribute__((ext_vector_type(4))) float f32x4;
typedef __attribute__((ext_vector_type(4))) unsigned u32x4;
typedef __attribute__((ext_vector_type(8))) short short8;

// path tables: (l1,l2,l3) in reference order (sorted by l1)
constexpr int PL1[NPATH] = {0,0,0,0, 1,1,1,1,1,1,1,1,1, 2,2,2,2,2,2,2,2,2,2,2, 3,3,3,3,3,3,3,3,3,3};
constexpr int PL2[NPATH] = {0,1,2,3, 0,1,1,1,2,2,2,3,3, 0,1,1,1,2,2,2,2,3,3,3, 0,1,1,2,2,2,3,3,3,3};
constexpr int PL3[NPATH] = {0,1,2,3, 1,0,1,2,1,2,3,2,3, 2,1,2,3,0,1,2,3,1,2,3, 3,2,3,1,2,3,0,1,2,3};
// pair-padded cg offsets: per path size S3*S2*(S1+1), layout [k][j][i(pad even)]
constexpr int PCGF[NPATH] = {0,2,20,70, 168,180,192,228,288,348,448,588,728,
                             924,954,1008,1098,1224,1254,1344,1494,1704,1830,2040,
                             2334,2390,2510,2678,2798,2998,3278,3334,3502,3782};
// i-pair slot offsets per l1 block in x2s (widths {1,2,3,4}, 10 total)
constexpr int PO1A[4] = {0, 1, 3, 6};

__device__ __forceinline__ short f2bf(float f){
  unsigned u = __float_as_uint(f);
  unsigned r = (u + 0x7fffu + ((u >> 16) & 1u)) >> 16;
  return (short)r;
}

// ---- packed-math helpers (VOP3P asm verified on-device rounds 3-13) -------
__device__ __forceinline__ f32x2 pk_fma(f32x2 a, f32x2 x, f32x2 b){
  asm("v_pk_fma_f32 %0, %1, %2, %0" : "+v"(a) : "v"(x), "v"(b));
  return a;
}
__device__ __forceinline__ unsigned cvt_pk_bf16(float lo, float hi){
  unsigned r;
  asm("v_cvt_pk_bf16_f32 %0, %1, %2" : "=v"(r) : "v"(lo), "v"(hi));
  return r;
}
// c += a.lo*b.lo + a.hi*b.hi   (2x bf16 FMA, f32 accumulate)
__device__ __forceinline__ float dot2bf(unsigned a, unsigned b, float c){
  asm("v_dot2_f32_bf16 %0, %1, %2, %0" : "+v"(c) : "v"(a), "v"(b));
  return c;
}

// ------------------------------ prep_cgf -----------------------------------
__device__ double factd(int n){
  double f = 1.0;
  for (int i = 2; i <= n; i++) f *= (double)i;
  return f;
}

__device__ double cg_complex(int j1,int m1,int j2,int m2,int j3,int m3){
  if (m1 + m2 != m3) return 0.0;
  int dj = j1 - j2; if (dj < 0) dj = -dj;
  if (j3 < dj || j3 > j1 + j2) return 0.0;
  double pre = sqrt((double)(2*j3+1) * factd(j3+j1-j2) * factd(j3-j1+j2) *
                    factd(j1+j2-j3) / factd(j1+j2+j3+1));
  pre *= sqrt(factd(j3+m3)*factd(j3-m3)*factd(j1-m1)*factd(j1+m1)*
              factd(j2-m2)*factd(j2+m2));
  int k0 = 0;
  if (j2-j3-m1 > k0) k0 = j2-j3-m1;
  if (j1+m2-j3 > k0) k0 = j1+m2-j3;
  int k1 = j1+j2-j3;
  if (j1-m1 < k1) k1 = j1-m1;
  if (j2+m2 < k1) k1 = j2+m2;
  double s = 0.0;
  for (int k = k0; k <= k1; k++){
    double d = factd(k)*factd(j1+j2-j3-k)*factd(j1-m1-k)*factd(j2+m2-k)*
               factd(j3-j2+m1+k)*factd(j3-j1-m2+k);
    s += ((k & 1) ? -1.0 : 1.0) / d;
  }
  return pre * s;
}

struct Uent { int m; double re, im; };

__device__ int urow(int l, int a, Uent* o){
  const double s2 = 0.70710678118654752440;
  int ra = a - l;
  if (ra == 0){ o[0] = {0, 1.0, 0.0}; return 1; }
  if (ra > 0){
    int m = ra;
    o[0] = { -m, s2, 0.0 };
    o[1] = {  m, (m & 1) ? -s2 : s2, 0.0 };
    return 2;
  }
  int m = -ra;
  o[0] = { -m, 0.0, s2 };
  o[1] = {  m, 0.0, (m & 1) ? s2 : -s2 };
  return 2;
}

__device__ float real_cg(int l1, int l2, int l3, int i, int j, int k){
  Uent u1[2], u2[2], u3[2];
  int n1 = urow(l1, i, u1), n2 = urow(l2, j, u2), n3 = urow(l3, k, u3);
  double sre = 0.0, sim = 0.0;
  for (int a = 0; a < n1; a++)
    for (int b = 0; b < n2; b++)
      for (int c = 0; c < n3; c++){
        double cr = u1[a].re*u2[b].re - u1[a].im*u2[b].im;
        double ci = u1[a].re*u2[b].im + u1[a].im*u2[b].re;
        double tr = cr*u3[c].re + ci*u3[c].im;   // times conj(u3)
        double ti = ci*u3[c].re - cr*u3[c].im;
        double cgv = cg_complex(l1, u1[a].m, l2, u2[b].m, l3, u3[c].m);
        sre += tr*cgv; sim += ti*cgv;
      }
  return (float)((((l1+l2+l3) & 1) == 0) ? sre : sim);
}

// writes cgf[slot] with slot = PCGF[p] + (k*S2 + j)*(S1+1) + i  (i pad -> 0)
__global__ void prep_cgf(float* __restrict__ cgf){
  int idx = blockIdx.x * blockDim.x + threadIdx.x;
  if (idx >= TOTCGF) return;
  int p = 0;
  for (int q = 1; q < NPATH; q++) if (idx >= PCGF[q]) p = q;
  const int l1 = PL1[p], l2 = PL2[p], l3 = PL3[p];
  const int S1 = 2*l1+1, S2 = 2*l2+1, S1p = S1+1;
  int q  = idx - PCGF[p];
  int kkj = q / S1p;
  int ii  = q - kkj*S1p;
  float v = 0.f;
  if (ii < S1){
    int kk = kkj / S2;
    int j  = kkj - kk*S2;
    v = real_cg(l1, l2, l3, ii, j, kk);
  }
  cgf[idx] = v;
}

// ------------------------------ prep_w -------------------------------------
// wt[p][d][c] = bf16(tpw[p][c][d]);  Wb[o][ia] = bf16(W[o][(ia&31)*16 + (ia>>5)])
__global__ void prep_w(const float* __restrict__ tpw, const float* __restrict__ lw,
                       short* __restrict__ wt, short* __restrict__ Wb){
  int idx = blockIdx.x * blockDim.x + threadIdx.x;
  if (idx < NPATH*1024){
    int c = idx & 31, d = (idx >> 5) & 31, p = idx >> 10;
    wt[idx] = f2bf(tpw[(p << 10) + c*32 + d]);
  } else if (idx < NPATH*1024 + 512*512){
    int q = idx - NPATH*1024;
    int o = q >> 9, ia = q & 511;
    Wb[q] = f2bf(lw[o*512 + ((ia & 31) << 4) + (ia >> 5)]);
  }
}

// --------------------------- sort-by-dst prep ------------------------------
__global__ void k_count(const int* __restrict__ ei, int* __restrict__ cnt, int E){
  int e = blockIdx.x*256 + threadIdx.x;
  if (e < E) atomicAdd(&cnt[ei[E + e]], 1);
}

__global__ void k_scan(int* __restrict__ cnt, int N){
  __shared__ int part[256];
  const int t = threadIdx.x;
  const int base = t * 40;
  int loc[40];
  int s = 0;
  #pragma unroll
  for (int q = 0; q < 40; q++){
    int idx = base + q;
    int v = (idx < N) ? cnt[idx] : 0;
    loc[q] = s; s += v;
  }
  part[t] = s;
  __syncthreads();
  for (int d = 1; d < 256; d <<= 1){
    int v = (t >= d) ? part[t - d] : 0;
    __syncthreads();
    part[t] += v;
    __syncthreads();
  }
  int pre = (t == 0) ? 0 : part[t - 1];
  #pragma unroll
  for (int q = 0; q < 40; q++){
    int idx = base + q;
    if (idx < N) cnt[idx] = pre + loc[q];
  }
}

__global__ void k_fill(const int* __restrict__ ei, int* __restrict__ cur,
                       int* __restrict__ perm, int E){
  int e = blockIdx.x*256 + threadIdx.x;
  if (e < E){
    int pos = atomicAdd(&cur[ei[E + e]], 1);
    perm[pos] = e;
  }
}

// --------------------------- path expansion helper -------------------------
template<typename F, size_t... I>
__device__ __forceinline__ void for_each_path(F&& f, std::index_sequence<I...>){
  (f(std::integral_constant<size_t, I>{}), ...);
}

// row swizzle for x2s: bits 2-4 of dword index, keeps b128 alignment
__device__ __forceinline__ int xswz(int r){
  return ((r & 3) << 2) | ((r & 1) << 4);
}

// ------------------------------ edge kernel --------------------------------
// 256 threads (4 waves), 16 dst-sorted edges/block. kg%4==wv wave split
// (wv scalarized). Lane role: lw = lane&15 (edge), g = lane>>4 (ch chunk).
__global__ __launch_bounds__(256, 4) void edge_kernel(
    const float* __restrict__ nf, const int* __restrict__ ei,
    const float* __restrict__ ev, const float* __restrict__ cgfg,
    const short* __restrict__ wt, const int* __restrict__ perm,
    float* __restrict__ accb, int E, int N)
{
  // phase1: x2s[10][16][32] u32 [0,20480) + Ydup f32x2[16][17] [20480,22656)
  // phase2: acc_l[16][256] f32 [0,16384)   (time-disjoint overlay of x2s)
  __shared__ __align__(16) char u_lds[22656];
  unsigned* x2s   = (unsigned*)u_lds;
  f32x2*    Yl2   = (f32x2*)(u_lds + 20480);
  float*    acc_l = (float*)u_lds;
  __shared__ __align__(16) float cgl[TOTCGF];          // 16696 B
  __shared__ int sdst[16];

  const int t    = threadIdx.x;
  const int lane = t & 63;
  const int wv   = __builtin_amdgcn_readfirstlane(t >> 6);  // SCALAR wave id
  const int e0   = blockIdx.x * 16;

  // ---- prologue: stage cg table into LDS (17 coalesced loads/thread) ----
  for (int i = t; i < TOTCGF; i += 256) cgl[i] = cgfg[i];

  // ---- prologue: permuted edge meta + Y (first 16 threads) ----
  if (t < 16){
    int eg = e0 + t;
    int pe = (eg < E) ? perm[eg] : -1;
    float vx = 0.f, vy = 0.f, vz = 0.f; int dn = -1;
    if (pe >= 0){
      vx = ev[pe*3]; vy = ev[pe*3+1]; vz = ev[pe*3+2];
      dn = ei[E + pe];
    }
    float nrm = sqrtf(vx*vx + vy*vy + vz*vz);
    float inv = 1.0f / fmaxf(nrm, 1e-8f);
    float x = vx*inv, y = vy*inv, z = vz*inv;
    float x2 = x*x, y2 = y*y, z2 = z*z;
    float ys[16];
    ys[0]  = 0.28209479177387814f;
    ys[1]  = 0.4886025119029199f * y;
    ys[2]  = 0.4886025119029199f * z;
    ys[3]  = 0.4886025119029199f * x;
    ys[4]  = 1.0925484305920792f * x * y;
    ys[5]  = 1.0925484305920792f * y * z;
    ys[6]  = 0.31539156525252005f * (3.f*z2 - 1.f);
    ys[7]  = 1.0925484305920792f * x * z;
    ys[8]  = 0.5462742152960396f * (x2 - y2);
    ys[9]  = 0.5900435899266435f * y * (3.f*x2 - y2);
    ys[10] = 2.890611442640554f * x * y * z;
    ys[11] = 0.4570457994644658f * y * (5.f*z2 - 1.f);
    ys[12] = 0.3731763325901154f * z * (5.f*z2 - 3.f);
    ys[13] = 0.4570457994644658f * x * (5.f*z2 - 1.f);
    ys[14] = 1.445305721320277f * z * (x2 - y2);
    ys[15] = 0.5900435899266435f * x * (x2 - 3.f*y2);
    #pragma unroll
    for (int j = 0; j < 16; j++) Yl2[t*17 + j] = (f32x2){ys[j], ys[j]};
    sdst[t] = dn;
  }

  // ---- prologue: x gather (once, coalesced) -> packed bf16 pairs in x2s ----
  {
    const int el = t >> 4, c0 = t & 15;
    int eg = e0 + el;
    int pe = (eg < E) ? perm[eg] : -1;
    int s  = (pe >= 0) ? ei[pe] : 0;
    const float* xb = nf + (size_t)s * 512;
    const int sw = xswz(el);
    #pragma unroll
    for (int h = 0; h < 2; h++){
      const int c = c0 + 16*h;
      const float* rp = xb + c * 16;
      f32x4 v0 = ((const f32x4*)rp)[0];
      f32x4 v1 = ((const f32x4*)rp)[1];
      f32x4 v2 = ((const f32x4*)rp)[2];
      f32x4 v3 = ((const f32x4*)rp)[3];
      unsigned d[10];
      d[0] = cvt_pk_bf16(v0[0], 0.f);          // l1=0: (i0, pad)
      d[1] = cvt_pk_bf16(v0[1], v0[2]);        // l1=1: (i1,i2)
      d[2] = cvt_pk_bf16(v0[3], 0.f);          //        (i3, pad)
      d[3] = cvt_pk_bf16(v1[0], v1[1]);        // l1=2: (i4,i5)
      d[4] = cvt_pk_bf16(v1[2], v1[3]);        //        (i6,i7)
      d[5] = cvt_pk_bf16(v2[0], 0.f);          //        (i8, pad)
      d[6] = cvt_pk_bf16(v2[1], v2[2]);        // l1=3: (i9,i10)
      d[7] = cvt_pk_bf16(v2[3], v3[0]);        //        (i11,i12)
      d[8] = cvt_pk_bf16(v3[1], v3[2]);        //        (i13,i14)
      d[9] = cvt_pk_bf16(v3[3], 0.f);          //        (i15, pad)
      #pragma unroll
      for (int ip = 0; ip < 10; ip++)
        x2s[ip*512 + el*32 + (c ^ sw)] = d[ip];
    }
  }

  f32x4 accm[4][2];
  #pragma unroll
  for (int q = 0; q < 4; q++){
    accm[q][0] = (f32x4){0.f,0.f,0.f,0.f};
    accm[q][1] = (f32x4){0.f,0.f,0.f,0.f};
  }

  __syncthreads();   // cgl / x2s / Yl2 / sdst visible

  const int lw   = lane & 15;
  const int g    = lane >> 4;
  const int swr  = xswz(lw);
  const int lwx4 = lw * 4;          // bpermute byte index base

  unsigned xs[8][4] = {};

  auto pbody = [&](auto pc){
    constexpr int P   = (int)decltype(pc)::value;
    constexpr int L1v = PL1[P], L2v = PL2[P], L3v = PL3[P];
    constexpr int S1 = 2*L1v+1, S2 = 2*L2v+1, S3 = 2*L3v+1;
    constexpr int O2 = L2v*L2v, O3 = L3v*L3v;
    constexpr int S1p  = S1 + 1;
    constexpr int S1p2 = S1p / 2;
    constexpr int CGF  = PCGF[P];
    constexpr int PO   = PO1A[L1v];

    // ---- group head: x fragments LDS -> registers ----
    if constexpr (P == 0 || PL1[P] != PL1[P-1]){
      #pragma unroll
      for (int ip = 0; ip < S1p2; ip++){
        const int base = (PO + ip)*512 + lw*32;
        u32x4 xlo = *(const u32x4*)&x2s[base + ((8*g)     ^ swr)];
        u32x4 xhi = *(const u32x4*)&x2s[base + ((8*g + 4) ^ swr)];
        xs[0][ip] = xlo[0]; xs[1][ip] = xlo[1];
        xs[2][ip] = xlo[2]; xs[3][ip] = xlo[3];
        xs[4][ip] = xhi[0]; xs[5][ip] = xhi[1];
        xs[6][ip] = xhi[2]; xs[7][ip] = xhi[3];
      }
    }

    // wave participates? (wv is SGPR -> scalar branch)
    bool hasrow;
    if constexpr (S3 >= 4) hasrow = true;
    else hasrow = (((unsigned)(wv - O3) & 3u) < (unsigned)S3);
    if (!hasrow) return;

    // weight fragments (global, L2-hot)
    const short8 bw0 = *(const short8*)(wt + (size_t)(P*32 +      lw)*32 + g*8);
    const short8 bw1 = *(const short8*)(wt + (size_t)(P*32 + 16 + lw)*32 + g*8);

    #pragma unroll
    for (int kl = 0; kl < S3; kl++){
      if (((O3 + kl) & 3) == wv){        // SCALAR compare -> s_cbranch
        // ---- B-comp: lane g computes ONLY pair-slot ip=g (1x issue) ----
        unsigned bq_own = 0;
        if (g < S1p2){
          f32x2 bacc = {0.f, 0.f};
          #pragma unroll
          for (int j = 0; j < S2; j++)
            bacc = pk_fma(bacc,
                          *(const f32x2*)&cgl[CGF + (kl*S2 + j)*S1p + 2*g],
                          Yl2[lw*17 + O2 + j]);
          bq_own = cvt_pk_bf16(bacc.x, bacc.y);
        }
        // broadcast the S1p2 slots wave-locally (src lane = lw + 16*ip)
        unsigned bq[4];
        #pragma unroll
        for (int ip = 0; ip < S1p2; ip++)
          bq[ip] = (unsigned)__builtin_amdgcn_ds_bpermute(lwx4 + 64*ip,
                                                          (int)bq_own);
        // ---- a-comp: lane's own A-fragment (8 channels) via dot2 ----
        float ac[8];
        #pragma unroll
        for (int q = 0; q < 8; q++) ac[q] = 0.f;
        #pragma unroll
        for (int ip = 0; ip < S1p2; ip++){
          #pragma unroll
          for (int q = 0; q < 8; q++)
            ac[q] = dot2bf(xs[q][ip], bq[ip], ac[q]);
        }
        union { unsigned u[4]; short8 s; } afu;
        afu.u[0] = cvt_pk_bf16(ac[0], ac[1]);
        afu.u[1] = cvt_pk_bf16(ac[2], ac[3]);
        afu.u[2] = cvt_pk_bf16(ac[4], ac[5]);
        afu.u[3] = cvt_pk_bf16(ac[6], ac[7]);
        // ---- MFMA: C[e][d] += a[e][c] * w[c][d], d-halves 0/1 ----
        const int ks = (O3 + kl) >> 2;
        accm[ks][0] = __builtin_amdgcn_mfma_f32_16x16x32_bf16(afu.s, bw0, accm[ks][0], 0, 0, 0);
        accm[ks][1] = __builtin_amdgcn_mfma_f32_16x16x32_bf16(afu.s, bw1, accm[ks][1], 0, 0, 0);
      }
    }
  };
  for_each_path(pbody, std::make_index_sequence<NPATH>{});

  __syncthreads();   // all x2s reads done before acc_l overlay

  // ---- epilogue: two half-tiles (kg 0..7 then 8..15), run-flush each ----
  #pragma unroll
  for (int half = 0; half < 2; half++){
    #pragma unroll
    for (int ks2 = 0; ks2 < 2; ks2++){
      const int ks = half*2 + ks2;
      const int kg = wv + 4*ks;
      #pragma unroll
      for (int dt2 = 0; dt2 < 2; dt2++){
        const int d = dt2*16 + lw;
        #pragma unroll
        for (int r = 0; r < 4; r++){
          const int e = 4*g + r;
          acc_l[(e*256 + (kg & 7)*32 + d) ^ (g << 3)] = accm[ks][dt2][r];
        }
      }
    }
    __syncthreads();
    {
      const int c = t;
      float v = 0.f; int prev = -2;
      #pragma unroll
      for (int s = 0; s < 16; s++){
        int dn = __builtin_amdgcn_readfirstlane(sdst[s]);  // block-uniform
        float av = acc_l[(s*256 + c) ^ (((s >> 2) & 3) << 3)];
        if (dn != prev){
          if (prev >= 0) unsafeAtomicAdd(accb + (size_t)prev*512 + half*256 + c, v);
          v = 0.f; prev = dn;
        }
        v += av;
      }
      if (prev >= 0) unsafeAtomicAdd(accb + (size_t)prev*512 + half*256 + c, v);
    }
    if (half == 0) __syncthreads();   // flush reads done before next writes
  }
}

// ------------------------------ linear kernel ------------------------------
__global__ __launch_bounds__(256, 4) void lin_kernel(
    const float* __restrict__ accb, const short* __restrict__ Wb,
    const float* __restrict__ bias, float* __restrict__ out, int N)
{
  __shared__ __align__(16) short As[64][32];
  __shared__ __align__(16) short Ws[64][32];
  const int t = threadIdx.x;
  const int lane = t & 63, wv = t >> 6;
  const int n0 = blockIdx.x * 64, o0 = blockIdx.y * 64;
  f32x4 acc4[4];
  #pragma unroll
  for (int q = 0; q < 4; q++) acc4[q] = (f32x4){0.f, 0.f, 0.f, 0.f};

  const int nn = t >> 2, kq = (t & 3) * 8;
  for (int kc = 0; kc < 16; kc++){
    __syncthreads();
    {
      short8 v8;
      int gn = n0 + nn;
      if (gn < N){
        const float* sp = accb + (size_t)gn*512 + kc*32 + kq;
        f32x4 f0 = ((const f32x4*)sp)[0], f1 = ((const f32x4*)sp)[1];
        v8[0] = f2bf(f0[0]); v8[1] = f2bf(f0[1]); v8[2] = f2bf(f0[2]); v8[3] = f2bf(f0[3]);
        v8[4] = f2bf(f1[0]); v8[5] = f2bf(f1[1]); v8[6] = f2bf(f1[2]); v8[7] = f2bf(f1[3]);
      } else {
        #pragma unroll
        for (int q = 0; q < 8; q++) v8[q] = 0;
      }
      *(short8*)&As[nn][kq] = v8;
      *(short8*)&Ws[nn][kq] = *(const short8*)(Wb + (size_t)(o0 + nn)*512 + kc*32 + kq);
    }
    __syncthreads();
    const short8 af = *(const short8*)&As[wv*16 + (lane & 15)][(lane >> 4) * 8];
    #pragma unroll
    for (int ct = 0; ct < 4; ct++){
      short8 bf8 = *(const short8*)&Ws[ct*16 + (lane & 15)][(lane >> 4) * 8];
      acc4[ct] = __builtin_amdgcn_mfma_f32_16x16x32_bf16(af, bf8, acc4[ct], 0, 0, 0);
    }
  }

  #pragma unroll
  for (int ct = 0; ct < 4; ct++){
    int o = o0 + ct*16 + (lane & 15);
    float bb = bias[o];
    #pragma unroll
    for (int r = 0; r < 4; r++){
      int n = n0 + wv*16 + (lane >> 4)*4 + r;
      if (n < N)
        out[(size_t)n*512 + o] = acc4[ct][r] + bb;
    }
  }
}

// ------------------------------ launcher -----------------------------------
extern "C" void kernel_launch(void* const* d_in, const int* in_sizes, int n_in,
                              void* d_out, int out_size, void* d_ws, size_t ws_size,
                              hipStream_t stream) {
  const float* nf  = (const float*)d_in[0];   // node_features (N,32,16) f32
  const int*   ei  = (const int*)d_in[1];     // edge_index (2,E) i32
  const float* ev  = (const float*)d_in[2];   // edge_vectors (E,3) f32
  const float* tpw = (const float*)d_in[3];   // tp_weights (34,32,32) f32
  const float* lw  = (const float*)d_in[4];   // linear_w (512,512) f32
  const float* lb  = (const float*)d_in[5];   // linear_b (512,) f32

  const int N = in_sizes[0] / 512;
  const int E = in_sizes[1] / 2;

  char* ws = (char*)d_ws;
  size_t off = 0;
  float* accb = (float*)(ws + off);
  off += (size_t)N * 512 * 4;          off = (off + 255) & ~(size_t)255;
  float* cgfg = (float*)(ws + off);
  off += (size_t)TOTCGF * 4;           off = (off + 255) & ~(size_t)255;
  short* wt   = (short*)(ws + off);
  off += (size_t)NPATH * 1024 * 2;     off = (off + 255) & ~(size_t)255;
  short* Wb   = (short*)(ws + off);
  off += (size_t)512 * 512 * 2;        off = (off + 255) & ~(size_t)255;
  int* cnt    = (int*)(ws + off);
  off += (size_t)N * 4;                off = (off + 255) & ~(size_t)255;
  int* perm   = (int*)(ws + off);
  off += (size_t)E * 4;
  if (off > ws_size) return;  // workspace too small: fail loudly via validation

  hipMemsetAsync(accb, 0, (size_t)N * 512 * 4, stream);
  hipMemsetAsync(cnt, 0, (size_t)N * 4, stream);
  k_count<<<(E + 255) / 256, 256, 0, stream>>>(ei, cnt, E);
  k_scan<<<1, 256, 0, stream>>>(cnt, N);
  k_fill<<<(E + 255) / 256, 256, 0, stream>>>(ei, cnt, perm, E);
  prep_cgf<<<(TOTCGF + 255) / 256, 256, 0, stream>>>(cgfg);
  prep_w<<<(NPATH*1024 + 512*512 + 255) / 256, 256, 0, stream>>>(tpw, lw, wt, Wb);
  edge_kernel<<<(E + 15) / 16, 256, 0, stream>>>(nf, ei, ev, cgfg, wt, perm,
                                                 accb, E, N);
  lin_kernel<<<dim3((N + 63) / 64, 8), 256, 0, stream>>>(accb, Wb, lb,
                                                         (float*)d_out, N);
}